// Round 3
// baseline (384.921 us; speedup 1.0000x reference)
//
#include <hip/hip_runtime.h>
#include <hip/hip_bf16.h>
#include <cstdint>

typedef __bf16 bf16;
typedef __bf16 bf16x8 __attribute__((ext_vector_type(8)));
typedef float floatx4 __attribute__((ext_vector_type(4)));

#define MFMA16(a, b, c) __builtin_amdgcn_mfma_f32_16x16x32_bf16(a, b, c, 0, 0, 0)
#define EXP2F(x) __builtin_amdgcn_exp2f(x)

__device__ __forceinline__ void gload_lds16(const void* g, void* l) {
  __builtin_amdgcn_global_load_lds(
      (const __attribute__((address_space(1))) unsigned int*)g,
      (__attribute__((address_space(3))) unsigned int*)l, 16, 0, 0);
}

// ---------------------------------------------------------------------------
// fp32 -> bf16 conversion: x (8M), Wq/Wk/Wv -> packed wqkv (3M), Wp (1M)
// ---------------------------------------------------------------------------
__global__ void convert_kernel(const float* __restrict__ x,
                               const float* __restrict__ wq,
                               const float* __restrict__ wk,
                               const float* __restrict__ wv,
                               const float* __restrict__ wp,
                               bf16* __restrict__ xb,
                               bf16* __restrict__ wqkvb,
                               bf16* __restrict__ wpb) {
  const long MB = 1024L * 1024L;
  long i = ((long)blockIdx.x * 256 + threadIdx.x) * 4;
  const float* src;
  bf16* dst;
  long off;
  if (i < 8 * MB)        { src = x;  dst = xb;          off = i; }
  else if (i < 9 * MB)   { src = wq; dst = wqkvb;       off = i - 8 * MB; }
  else if (i < 10 * MB)  { src = wk; dst = wqkvb + MB;  off = i - 9 * MB; }
  else if (i < 11 * MB)  { src = wv; dst = wqkvb + 2*MB; off = i - 10 * MB; }
  else                   { src = wp; dst = wpb;         off = i - 11 * MB; }
  float4 v = *(const float4*)(src + off);
  union { ushort4 u4; bf16 h[4]; } u;
  u.h[0] = (bf16)v.x; u.h[1] = (bf16)v.y; u.h[2] = (bf16)v.z; u.h[3] = (bf16)v.w;
  *(ushort4*)(dst + off) = u.u4;
}

// ---------------------------------------------------------------------------
// QKV GEMM: [8192,1024] x [3072,1024]^T, 128x128 tile, BK=32, dbuf LDS
// (32 KB -> 5 blocks/CU), counted-vmcnt pipeline, raw s_barrier, XCD-chunked
// block swizzle (each XCD owns 8 contiguous m-rows; 8 consecutive blocks
// share one B panel -> per-XCD L2 working set ~2.25 MB).
// ---------------------------------------------------------------------------
__global__ __launch_bounds__(256, 5) void gemm_qkv(
    const bf16* __restrict__ A, const bf16* __restrict__ Bw,
    const float* __restrict__ bq, const float* __restrict__ bk,
    const float* __restrict__ bv,
    bf16* __restrict__ qb, bf16* __restrict__ kb,
    float* __restrict__ pk, float* __restrict__ pv) {
  __shared__ __align__(16) bf16 As[2][128 * 32];  // 8 KB each buf
  __shared__ __align__(16) bf16 Bs[2][128 * 32];
  const int tid = threadIdx.x;
  const int lane = tid & 63, wid = tid >> 6;
  const int quad = lane >> 4, l15 = lane & 15;
  const int wm = wid >> 1, wn = wid & 1;

  // bijective XCD swizzle: grid (24,64) -> 1536 blocks, 192/XCD
  const int lin = blockIdx.y * 24 + blockIdx.x;
  const int xcd = lin & 7, j = lin >> 3;      // j in [0,192)
  const int bx = j >> 3;                      // [0,24) n-tile
  const int by = (xcd << 3) | (j & 7);        // [0,64) m-tile
  const long m0 = (long)by * 128;
  const long n0 = (long)bx * 128;

  // staging: granule s in {tid, tid+256}; row = s>>2, slot = s&3,
  // global k-granule = slot ^ (row&3) (pre-swizzled source, linear LDS dest)
  const int rA = tid >> 2, gA = (tid & 3) ^ (rA & 3);
  const bf16* a0 = A + (m0 + rA) * 1024 + gA * 8;
  const bf16* a1 = A + (m0 + rA + 64) * 1024 + gA * 8;  // (rA+64)&3 == rA&3
  const bf16* b0 = Bw + (n0 + rA) * 1024 + gA * 8;
  const bf16* b1 = Bw + (n0 + rA + 64) * 1024 + gA * 8;

#define QKV_STAGE(buf, k0)                              \
  {                                                     \
    gload_lds16(a0 + (k0), &As[buf][tid * 8]);          \
    gload_lds16(a1 + (k0), &As[buf][(tid + 256) * 8]);  \
    gload_lds16(b0 + (k0), &Bs[buf][tid * 8]);          \
    gload_lds16(b1 + (k0), &Bs[buf][(tid + 256) * 8]);  \
  }

  floatx4 acc[4][4] = {};

  QKV_STAGE(0, 0);
  for (int kt = 0; kt < 32; kt++) {
    const int cur = kt & 1;
    if (kt < 31) {
      QKV_STAGE(cur ^ 1, (kt + 1) * 32);
      asm volatile("s_waitcnt vmcnt(4)" ::: "memory");  // tile kt landed
    } else {
      asm volatile("s_waitcnt vmcnt(0)" ::: "memory");
    }
    __builtin_amdgcn_s_barrier();
    asm volatile("" ::: "memory");
    const bf16* Ac = &As[cur][0];
    const bf16* Bc = &Bs[cur][0];
    bf16x8 af[4], bfr[4];
#pragma unroll
    for (int mi = 0; mi < 4; mi++) {
      int row = wm * 64 + mi * 16 + l15;
      af[mi] = *(const bf16x8*)(Ac + row * 32 + ((quad ^ (row & 3)) * 8));
    }
#pragma unroll
    for (int ni = 0; ni < 4; ni++) {
      int row = wn * 64 + ni * 16 + l15;
      bfr[ni] = *(const bf16x8*)(Bc + row * 32 + ((quad ^ (row & 3)) * 8));
    }
    __builtin_amdgcn_s_setprio(1);
#pragma unroll
    for (int mi = 0; mi < 4; mi++)
#pragma unroll
      for (int ni = 0; ni < 4; ni++)
        acc[mi][ni] = MFMA16(af[mi], bfr[ni], acc[mi][ni]);
    __builtin_amdgcn_s_setprio(0);
    __builtin_amdgcn_s_barrier();  // all reads of buf `cur` done before restage
    asm volatile("" ::: "memory");
  }
#undef QKV_STAGE

  const int type = (int)(n0 >> 10);  // 0=q 1=k 2=v (128-tile never crosses)
#pragma unroll
  for (int ni = 0; ni < 4; ni++) {
    const long n = n0 + wn * 64 + ni * 16 + l15;
    float bias;
    if (type == 0) bias = bq[n];
    else if (type == 1) bias = bk[n - 1024];
    else bias = bv[n - 2048];
#pragma unroll
    for (int mi = 0; mi < 4; mi++) {
      const long mb = m0 + wm * 64 + mi * 16 + quad * 4;
      floatx4 a = acc[mi][ni];
      if (type == 0) {
#pragma unroll
        for (int r = 0; r < 4; r++) qb[(mb + r) * 1024 + n] = (bf16)(a[r] + bias);
      } else if (type == 1) {
        const long kc = n - 1024;
        const int hh = (int)(kc >> 6), d = (int)(kc & 63);
        const long bb = mb >> 11, t = mb & 2047;
        const long base = ((bb * 16 + hh) * 2048 + t) * 64 + d;
#pragma unroll
        for (int r = 0; r < 4; r++) {
          float v_ = a[r] + bias;
          kb[base + r * 64] = (bf16)v_;
          pk[base + r * 64] = v_;
        }
      } else {
        const long vc = n - 2048;
        const int hh = (int)(vc >> 6), d = (int)(vc & 63);
        const long bb = mb >> 11, t = mb & 2047;
        const long pbase = ((bb * 16 + hh) * 2048 + t) * 64 + d;
#pragma unroll
        for (int r = 0; r < 4; r++) pv[pbase + r * 64] = a[r] + bias;
      }
    }
  }
}

// ---------------------------------------------------------------------------
// V transpose: pv fp32 [B,H,T,D] -> vtb bf16 [B,H,D,T], LDS-tiled 64x64
// ---------------------------------------------------------------------------
__global__ __launch_bounds__(256) void transpose_v(const float* __restrict__ pv,
                                                   bf16* __restrict__ vtb) {
  __shared__ bf16 tile[64][70];
  const int bh = blockIdx.y;
  const int t0 = blockIdx.x * 64;
  const int tdx = threadIdx.x;
  const float* src = pv + (long)bh * 2048 * 64 + (long)t0 * 64;
  const int c4 = (tdx & 15) * 4;
  const int rr = tdx >> 4;
#pragma unroll
  for (int p = 0; p < 4; p++) {
    const int t = rr + p * 16;
    float4 v = *(const float4*)(src + t * 64 + c4);
    tile[c4 + 0][t] = (bf16)v.x;
    tile[c4 + 1][t] = (bf16)v.y;
    tile[c4 + 2][t] = (bf16)v.z;
    tile[c4 + 3][t] = (bf16)v.w;
  }
  __syncthreads();
  bf16* dst = vtb + (long)bh * 64 * 2048 + t0;
#pragma unroll
  for (int p = 0; p < 4; p++) {
    const int d = rr + p * 16;
    union { ushort4 u4; bf16 h[4]; } u;
    u.h[0] = tile[d][c4 + 0];
    u.h[1] = tile[d][c4 + 1];
    u.h[2] = tile[d][c4 + 2];
    u.h[3] = tile[d][c4 + 3];
    *(ushort4*)(dst + (long)d * 2048 + c4) = u.u4;
  }
}

// ---------------------------------------------------------------------------
// Flash attention, 2 q-tiles/block {31-p, p} (33 tile-computes for every p ->
// balanced), fixed-max softmax, l via ones-rows of V.
// Grid (bh=64, p=16) = 1024 blocks = 4/CU co-resident (36.9 KB LDS via Qs
// overlay); same-bh blocks stride 64 in linear id -> same XCD -> K/V L2 reuse.
// ---------------------------------------------------------------------------
#define PSTRIDE 72

__global__ __launch_bounds__(256, 4) void attn_kernel(
    const bf16* __restrict__ qb, const bf16* __restrict__ kb,
    const bf16* __restrict__ vtb, bf16* __restrict__ yws) {
  // steady-state layout: Ks [0,8192) | Vts [8192,18432) | Ps [18432,36864)
  // transient Qs [0,16384) overlays Ks + Vts rows 0..63 (dead after hoist);
  // Vts ones-rows live at [16384,18432) -> never clobbered by Qs.
  __shared__ __align__(16) uint8_t smem[36864];
  bf16* Ks  = (bf16*)smem;              // [64][64]   8192 B
  bf16* Vts = (bf16*)(smem + 8192);     // [80][64]  10240 B (rows 64..79 ones)
  bf16* Ps  = (bf16*)(smem + 18432);    // 2 bufs x 4 waves x 16 x PSTRIDE
  bf16* Qs  = (bf16*)smem;              // transient [2][64][64] 16384 B

  const int tid = threadIdx.x, lane = tid & 63, wid = tid >> 6;
  const int quad = lane >> 4, l15 = lane & 15;
  const int bh = blockIdx.x, b = bh >> 4, h = bh & 15;
  const int p = blockIdx.y;
  const int qts[2] = {31 - p, p};  // descending activity; 31-p >= 16 > p
  const float NEG_INF = -__builtin_inff();
  const float SCL = 0.125f * 1.44269504088896340736f;  // 1/sqrt(64) * log2(e)
  const float M0 = 20.0f;

  // stage 2 Q tiles [64][64] each, granule-swizzled: 1024 granules / 256 thr
#pragma unroll
  for (int j = 0; j < 4; j++) {
    const int g = j * 256 + tid;
    const int t = g >> 9, s = g & 511;
    const int row = s >> 3, gg = (s & 7) ^ (row & 7);
    gload_lds16(qb + ((long)(b * 2048 + qts[t] * 64 + row)) * 1024 + h * 64 + gg * 8,
                Qs + t * 4096 + s * 8);
  }
  {  // ones rows of Vts (outside Qs overlay, never overwritten by staging)
    union { ushort4 u4; bf16 h[4]; } one;
    one.h[0] = one.h[1] = one.h[2] = one.h[3] = (bf16)1.0f;
    *(ushort4*)(Vts + 64 * 64 + tid * 4) = one.u4;
  }
  __syncthreads();

  // hoist loop-invariant Q fragments (2 tiles x 2 k-chunks)
  bf16x8 qf[2][2];
  {
    const int row = wid * 16 + l15;
#pragma unroll
    for (int t = 0; t < 2; t++)
#pragma unroll
      for (int ks = 0; ks < 2; ks++)
        qf[t][ks] = *(const bf16x8*)(Qs + t * 4096 + row * 64 +
                                     (((ks * 4 + quad) ^ (row & 7)) * 8));
  }
  __syncthreads();  // all waves done reading Qs before K/V staging overwrites

  const bf16* kbase = kb + ((long)bh) * (2048L * 64);
  const bf16* vbase = vtb + ((long)bh) * (64L * 2048);
  floatx4 o[2][5] = {};
  bf16* pw0 = Ps + wid * (16 * PSTRIDE);
  bf16* pw1 = pw0 + 4 * 16 * PSTRIDE;

  const int ktmax = qts[0];
  for (int kt = 0; kt <= ktmax; kt++) {
    const int k0 = kt * 64;
    const int nact = 1 + (kt <= qts[1]);
    {
      int s = tid;
      int row = s >> 3, gg = (s & 7) ^ (row & 7);
      gload_lds16(kbase + (long)(k0 + row) * 64 + gg * 8, Ks + s * 8);
      gload_lds16(vbase + (long)row * 2048 + k0 + gg * 8, Vts + s * 8);
      s = tid + 256; row = s >> 3; gg = (s & 7) ^ (row & 7);
      gload_lds16(kbase + (long)(k0 + row) * 64 + gg * 8, Ks + s * 8);
      gload_lds16(vbase + (long)row * 2048 + k0 + gg * 8, Vts + s * 8);
    }
    __syncthreads();

    // ---- S = Q K^T for active tiles, one pass over shared K fragments ----
    floatx4 S[2][4] = {};
    __builtin_amdgcn_s_setprio(1);
#pragma unroll
    for (int ni = 0; ni < 4; ni++) {
      const int row = ni * 16 + l15;
#pragma unroll
      for (int ks = 0; ks < 2; ks++) {
        bf16x8 kf = *(const bf16x8*)(Ks + row * 64 + (((ks * 4 + quad) ^ (row & 7)) * 8));
        S[0][ni] = MFMA16(qf[0][ks], kf, S[0][ni]);
        if (nact > 1) S[1][ni] = MFMA16(qf[1][ks], kf, S[1][ni]);
      }
    }
    __builtin_amdgcn_s_setprio(0);

    // ---- softmax -> P buffers -> PV ----
    {
      const bool d0 = (kt == qts[0]), d1 = (kt == qts[1]);
#pragma unroll
      for (int ni = 0; ni < 4; ni++)
#pragma unroll
        for (int r = 0; r < 4; r++) {
          float v0 = S[0][ni][r] * SCL - M0;
          if (d0 && (ni * 16 + l15 > wid * 16 + quad * 4 + r)) v0 = NEG_INF;
          pw0[(quad * 4 + r) * PSTRIDE + ni * 16 + l15] = (bf16)EXP2F(v0);
        }
      if (nact > 1) {
#pragma unroll
        for (int ni = 0; ni < 4; ni++)
#pragma unroll
          for (int r = 0; r < 4; r++) {
            float v1 = S[1][ni][r] * SCL - M0;
            if (d1 && (ni * 16 + l15 > wid * 16 + quad * 4 + r)) v1 = NEG_INF;
            pw1[(quad * 4 + r) * PSTRIDE + ni * 16 + l15] = (bf16)EXP2F(v1);
          }
      }
      asm volatile("s_waitcnt lgkmcnt(0)" ::: "memory");
      bf16x8 pf0[2], pf1[2];
#pragma unroll
      for (int ks = 0; ks < 2; ks++)
        pf0[ks] = *(const bf16x8*)(pw0 + l15 * PSTRIDE + ks * 32 + quad * 8);
      if (nact > 1) {
#pragma unroll
        for (int ks = 0; ks < 2; ks++)
          pf1[ks] = *(const bf16x8*)(pw1 + l15 * PSTRIDE + ks * 32 + quad * 8);
      }
      __builtin_amdgcn_s_setprio(1);
#pragma unroll
      for (int ni = 0; ni < 5; ni++) {
        const int vrow = ni * 16 + l15;
#pragma unroll
        for (int ks = 0; ks < 2; ks++) {
          bf16x8 vf = *(const bf16x8*)(Vts + vrow * 64 + (((ks * 4 + quad) ^ (vrow & 7)) * 8));
          o[0][ni] = MFMA16(pf0[ks], vf, o[0][ni]);
          if (nact > 1) o[1][ni] = MFMA16(pf1[ks], vf, o[1][ni]);
        }
      }
      __builtin_amdgcn_s_setprio(0);
    }
    __syncthreads();
  }

  // ---- epilogue: 2 tiles; l = o[t][4] ----
#pragma unroll
  for (int t = 0; t < 2; t++) {
    const int q0 = qts[t] * 64;
    float inv[4];
#pragma unroll
    for (int r = 0; r < 4; r++) inv[r] = 1.0f / o[t][4][r];
    const long ybase = ((long)(b * 2048 + q0 + wid * 16 + quad * 4)) * 1024 + h * 64;
#pragma unroll
    for (int ni = 0; ni < 4; ni++)
#pragma unroll
      for (int r = 0; r < 4; r++)
        yws[ybase + (long)r * 1024 + ni * 16 + l15] = (bf16)(o[t][ni][r] * inv[r]);
  }
}

// ---------------------------------------------------------------------------
// Output projection: [8192,1024] x [1024,1024]^T -> y fp32; same pipelined
// BK=32 dbuf structure as gemm_qkv, XCD-chunked swizzle.
// ---------------------------------------------------------------------------
__global__ __launch_bounds__(256, 5) void gemm_proj(
    const bf16* __restrict__ A, const bf16* __restrict__ Bw,
    const float* __restrict__ bp, float* __restrict__ y) {
  __shared__ __align__(16) bf16 As[2][128 * 32];
  __shared__ __align__(16) bf16 Bs[2][128 * 32];
  const int tid = threadIdx.x;
  const int lane = tid & 63, wid = tid >> 6;
  const int quad = lane >> 4, l15 = lane & 15;
  const int wm = wid >> 1, wn = wid & 1;

  // bijective XCD swizzle: grid (8,64) -> 512 blocks, 64/XCD
  const int lin = blockIdx.y * 8 + blockIdx.x;
  const int xcd = lin & 7, j = lin >> 3;      // j in [0,64)
  const int bx = j >> 3;                      // [0,8) n-tile
  const int by = (xcd << 3) | (j & 7);        // [0,64) m-tile
  const long m0 = (long)by * 128;
  const long n0 = (long)bx * 128;

  const int rA = tid >> 2, gA = (tid & 3) ^ (rA & 3);
  const bf16* a0 = A + (m0 + rA) * 1024 + gA * 8;
  const bf16* a1 = A + (m0 + rA + 64) * 1024 + gA * 8;
  const bf16* b0 = Bw + (n0 + rA) * 1024 + gA * 8;
  const bf16* b1 = Bw + (n0 + rA + 64) * 1024 + gA * 8;

#define PROJ_STAGE(buf, k0)                             \
  {                                                     \
    gload_lds16(a0 + (k0), &As[buf][tid * 8]);          \
    gload_lds16(a1 + (k0), &As[buf][(tid + 256) * 8]);  \
    gload_lds16(b0 + (k0), &Bs[buf][tid * 8]);          \
    gload_lds16(b1 + (k0), &Bs[buf][(tid + 256) * 8]);  \
  }

  floatx4 acc[4][4] = {};

  PROJ_STAGE(0, 0);
  for (int kt = 0; kt < 32; kt++) {
    const int cur = kt & 1;
    if (kt < 31) {
      PROJ_STAGE(cur ^ 1, (kt + 1) * 32);
      asm volatile("s_waitcnt vmcnt(4)" ::: "memory");
    } else {
      asm volatile("s_waitcnt vmcnt(0)" ::: "memory");
    }
    __builtin_amdgcn_s_barrier();
    asm volatile("" ::: "memory");
    const bf16* Ac = &As[cur][0];
    const bf16* Bc = &Bs[cur][0];
    bf16x8 af[4], bfr[4];
#pragma unroll
    for (int mi = 0; mi < 4; mi++) {
      int row = wm * 64 + mi * 16 + l15;
      af[mi] = *(const bf16x8*)(Ac + row * 32 + ((quad ^ (row & 3)) * 8));
    }
#pragma unroll
    for (int ni = 0; ni < 4; ni++) {
      int row = wn * 64 + ni * 16 + l15;
      bfr[ni] = *(const bf16x8*)(Bc + row * 32 + ((quad ^ (row & 3)) * 8));
    }
    __builtin_amdgcn_s_setprio(1);
#pragma unroll
    for (int mi = 0; mi < 4; mi++)
#pragma unroll
      for (int ni = 0; ni < 4; ni++)
        acc[mi][ni] = MFMA16(af[mi], bfr[ni], acc[mi][ni]);
    __builtin_amdgcn_s_setprio(0);
    __builtin_amdgcn_s_barrier();
    asm volatile("" ::: "memory");
  }
#undef PROJ_STAGE

#pragma unroll
  for (int ni = 0; ni < 4; ni++) {
    const long n = n0 + wn * 64 + ni * 16 + l15;
    const float bias = bp[n];
#pragma unroll
    for (int mi = 0; mi < 4; mi++) {
      const long mb = m0 + wm * 64 + mi * 16 + quad * 4;
      floatx4 a = acc[mi][ni];
#pragma unroll
      for (int r = 0; r < 4; r++) y[(mb + r) * 1024 + n] = a[r] + bias;
    }
  }
}

// ---------------------------------------------------------------------------
extern "C" void kernel_launch(void* const* d_in, const int* in_sizes, int n_in,
                              void* d_out, int out_size, void* d_ws, size_t ws_size,
                              hipStream_t stream) {
  const float* x  = (const float*)d_in[0];
  const float* Wq = (const float*)d_in[1];
  const float* bq = (const float*)d_in[2];
  const float* Wk = (const float*)d_in[3];
  const float* bk = (const float*)d_in[4];
  const float* Wv = (const float*)d_in[5];
  const float* bv = (const float*)d_in[6];
  const float* Wp = (const float*)d_in[7];
  const float* bp = (const float*)d_in[8];

  float* y  = (float*)d_out;                 // [B,T,C] = 8388608
  float* pk = y + 8388608;                   // present[0] = k [B,H,T,D]
  float* pv = pk + 8388608;                  // present[1] = v [B,H,T,D]

  uint8_t* ws = (uint8_t*)d_ws;
  bf16* xb    = (bf16*)(ws);                    // 16 MB  [8192,1024]
  bf16* wqkvb = (bf16*)(ws + (16L << 20));      //  6 MB  [3072,1024]
  bf16* wpb   = (bf16*)(ws + (22L << 20));      //  2 MB  [1024,1024]
  bf16* qb    = (bf16*)(ws + (24L << 20));      // 16 MB  [B,T,C]
  bf16* kbf   = (bf16*)(ws + (40L << 20));      // 16 MB  [B,H,T,D]
  bf16* vtb   = (bf16*)(ws + (56L << 20));      // 16 MB  [B,H,D,T]
  bf16* yws   = (bf16*)(ws + (72L << 20));      // 16 MB  [B,T,C]

  convert_kernel<<<12288, 256, 0, stream>>>(x, Wq, Wk, Wv, Wp, xb, wqkvb, wpb);
  gemm_qkv<<<dim3(24, 64), 256, 0, stream>>>(xb, wqkvb, bq, bk, bv, qb, kbf, pk, pv);
  transpose_v<<<dim3(32, 64), 256, 0, stream>>>(pv, vtb);
  attn_kernel<<<dim3(64, 16), 256, 0, stream>>>(qb, kbf, vtb, yws);
  gemm_proj<<<dim3(8, 64), 256, 0, stream>>>(yws, wpb, bp, y);
}

// Round 5
// 302.270 us; speedup vs baseline: 1.2734x; 1.2734x over previous
//
#include <hip/hip_runtime.h>
#include <hip/hip_bf16.h>
#include <cstdint>

typedef __bf16 bf16;
typedef __bf16 bf16x8 __attribute__((ext_vector_type(8)));
typedef float floatx4 __attribute__((ext_vector_type(4)));

#define MFMA16(a, b, c) __builtin_amdgcn_mfma_f32_16x16x32_bf16(a, b, c, 0, 0, 0)
#define EXP2F(x) __builtin_amdgcn_exp2f(x)

// Fused waitcnt+barrier: single asm with memory clobber so NO memory op can
// be scheduled across it in either direction (raw builtin s_barrier is not a
// compiler fence; a separate clobber leaves a reorder window).
#define BAR_VM(N)  asm volatile("s_waitcnt vmcnt(" #N ")\n\ts_barrier" ::: "memory")
#define BAR_LGKM0() asm volatile("s_waitcnt lgkmcnt(0)\n\ts_barrier" ::: "memory")

__device__ __forceinline__ void gload_lds16(const void* g, void* l) {
  __builtin_amdgcn_global_load_lds(
      (const __attribute__((address_space(1))) unsigned int*)g,
      (__attribute__((address_space(3))) unsigned int*)l, 16, 0, 0);
}

// ---------------------------------------------------------------------------
// fp32 -> bf16 conversion: x (8M), Wq/Wk/Wv -> packed wqkv (3M), Wp (1M)
// ---------------------------------------------------------------------------
__global__ void convert_kernel(const float* __restrict__ x,
                               const float* __restrict__ wq,
                               const float* __restrict__ wk,
                               const float* __restrict__ wv,
                               const float* __restrict__ wp,
                               bf16* __restrict__ xb,
                               bf16* __restrict__ wqkvb,
                               bf16* __restrict__ wpb) {
  const long MB = 1024L * 1024L;
  long i = ((long)blockIdx.x * 256 + threadIdx.x) * 4;
  const float* src;
  bf16* dst;
  long off;
  if (i < 8 * MB)        { src = x;  dst = xb;          off = i; }
  else if (i < 9 * MB)   { src = wq; dst = wqkvb;       off = i - 8 * MB; }
  else if (i < 10 * MB)  { src = wk; dst = wqkvb + MB;  off = i - 9 * MB; }
  else if (i < 11 * MB)  { src = wv; dst = wqkvb + 2*MB; off = i - 10 * MB; }
  else                   { src = wp; dst = wpb;         off = i - 11 * MB; }
  float4 v = *(const float4*)(src + off);
  union { ushort4 u4; bf16 h[4]; } u;
  u.h[0] = (bf16)v.x; u.h[1] = (bf16)v.y; u.h[2] = (bf16)v.z; u.h[3] = (bf16)v.w;
  *(ushort4*)(dst + off) = u.u4;
}

// ---------------------------------------------------------------------------
// QKV GEMM: [8192,1024] x [3072,1024]^T, 128x128 tile, BK=64, dbuf LDS,
// counted-vmcnt pipeline, race-hardened barriers (fused waitcnt+s_barrier,
// lgkmcnt(0) guard before restage), XCD-chunked block swizzle, fused
// V-transpose in epilogue (writes vtb bf16 [B,H,D,T] directly).
// ---------------------------------------------------------------------------
__global__ __launch_bounds__(256, 2) void gemm_qkv(
    const bf16* __restrict__ A, const bf16* __restrict__ Bw,
    const float* __restrict__ bq, const float* __restrict__ bk,
    const float* __restrict__ bv,
    bf16* __restrict__ qb, bf16* __restrict__ kb,
    float* __restrict__ pk, float* __restrict__ pv,
    bf16* __restrict__ vtb) {
  __shared__ __align__(16) bf16 As[2][128 * 64];  // 32 KB
  __shared__ __align__(16) bf16 Bs[2][128 * 64];  // 32 KB
  const int tid = threadIdx.x;
  const int lane = tid & 63, wid = tid >> 6;
  const int quad = lane >> 4, l15 = lane & 15;
  const int wm = wid >> 1, wn = wid & 1;

  // bijective XCD-chunked swizzle: grid (24,64) -> 1536 blocks, 192/XCD.
  // Same-XCD consecutive blocks share one B panel and walk 8 m-tiles.
  const int lin = blockIdx.y * 24 + blockIdx.x;
  const int xcd = lin & 7, j = lin >> 3;      // j in [0,192)
  const int bx = j >> 3;                      // [0,24) n-tile
  const int by = (xcd << 3) | (j & 7);        // [0,64) m-tile
  const long m0 = (long)by * 128;
  const long n0 = (long)bx * 128;

  // staging: granule s = tid + jj*256 (jj=0..3); row = s>>3, slot = s&7.
  // LDS (row, slot) holds global k-granule slot^(row&7)  [pre-swizzled
  // global source, linear LDS dest for global_load_lds]
  const int gg = (tid & 7) ^ ((tid >> 3) & 7);
  const bf16* aSrc = A + (m0 + (tid >> 3)) * 1024 + gg * 8;
  const bf16* bSrc = Bw + (n0 + (tid >> 3)) * 1024 + gg * 8;

#define QKV_STAGE(buf, k0)                                                  \
  {                                                                         \
    _Pragma("unroll")                                                       \
    for (int jj = 0; jj < 4; jj++) {                                        \
      gload_lds16(aSrc + (k0) + jj * (32 * 1024), &As[buf][(tid + jj * 256) * 8]); \
      gload_lds16(bSrc + (k0) + jj * (32 * 1024), &Bs[buf][(tid + jj * 256) * 8]); \
    }                                                                       \
  }

  floatx4 acc[4][4] = {};

  QKV_STAGE(0, 0);
  for (int kt = 0; kt < 16; kt++) {
    const int cur = kt & 1;
    if (kt < 15) {
      QKV_STAGE(cur ^ 1, (kt + 1) * 64);
      BAR_VM(8);  // own tile-kt loads landed; next-tile loads stay in flight
    } else {
      BAR_VM(0);
    }
    const bf16* Ac = &As[cur][0];
    const bf16* Bc = &Bs[cur][0];
    __builtin_amdgcn_s_setprio(1);
#pragma unroll
    for (int ks = 0; ks < 2; ks++) {
      bf16x8 af[4], bfr[4];
#pragma unroll
      for (int mi = 0; mi < 4; mi++) {
        int row = wm * 64 + mi * 16 + l15;
        af[mi] = *(const bf16x8*)(Ac + row * 64 + (((ks * 4 + quad) ^ (row & 7)) * 8));
      }
#pragma unroll
      for (int ni = 0; ni < 4; ni++) {
        int row = wn * 64 + ni * 16 + l15;
        bfr[ni] = *(const bf16x8*)(Bc + row * 64 + (((ks * 4 + quad) ^ (row & 7)) * 8));
      }
#pragma unroll
      for (int mi = 0; mi < 4; mi++)
#pragma unroll
        for (int ni = 0; ni < 4; ni++)
          acc[mi][ni] = MFMA16(af[mi], bfr[ni], acc[mi][ni]);
    }
    __builtin_amdgcn_s_setprio(0);
    // restage guard: this wave provably has 0 outstanding LDS reads before
    // any wave may pass the barrier and DMA-overwrite buf `cur`.
    BAR_LGKM0();
  }
#undef QKV_STAGE

  const int type = (int)(n0 >> 10);  // 0=q 1=k 2=v (128-tile never crosses)
#pragma unroll
  for (int ni = 0; ni < 4; ni++) {
    const long n = n0 + wn * 64 + ni * 16 + l15;
    float bias;
    if (type == 0) bias = bq[n];
    else if (type == 1) bias = bk[n - 1024];
    else bias = bv[n - 2048];
#pragma unroll
    for (int mi = 0; mi < 4; mi++) {
      const long mb = m0 + wm * 64 + mi * 16 + quad * 4;
      floatx4 a = acc[mi][ni];
      if (type == 0) {
#pragma unroll
        for (int r = 0; r < 4; r++) qb[(mb + r) * 1024 + n] = (bf16)(a[r] + bias);
      } else if (type == 1) {
        const long kc = n - 1024;
        const int hh = (int)(kc >> 6), d = (int)(kc & 63);
        const long bb = mb >> 11, t = mb & 2047;
        const long base = ((bb * 16 + hh) * 2048 + t) * 64 + d;
#pragma unroll
        for (int r = 0; r < 4; r++) {
          float v_ = a[r] + bias;
          kb[base + r * 64] = (bf16)v_;
          pk[base + r * 64] = v_;
        }
      } else {
        const long vc = n - 2048;
        const int hh = (int)(vc >> 6), d = (int)(vc & 63);
        const long bb = mb >> 11, t = mb & 2047;  // t multiple of 4
        const long pbase = ((bb * 16 + hh) * 2048 + t) * 64 + d;
        union { ushort4 u4; bf16 hx[4]; } uv;
#pragma unroll
        for (int r = 0; r < 4; r++) {
          float v_ = a[r] + bias;
          pv[pbase + r * 64] = v_;
          uv.hx[r] = (bf16)v_;
        }
        // fused transpose: vtb[B,H,D,T]; r walks t -> one aligned 8B store
        const long vtbase = ((bb * 16 + hh) * 64 + d) * 2048 + t;
        *(ushort4*)(vtb + vtbase) = uv.u4;
      }
    }
  }
}

// ---------------------------------------------------------------------------
// Flash attention, 2 q-tiles/block {31-p, p} (33 tile-computes for every p ->
// balanced), fixed-max softmax, l via ones-rows of V.
// Grid (bh=64, p=16) = 1024 blocks = 4/CU co-resident (36.9 KB LDS via Qs
// overlay); same-bh blocks stride 64 in linear id -> same XCD -> K/V L2 reuse.
// ---------------------------------------------------------------------------
#define PSTRIDE 72

__global__ __launch_bounds__(256, 4) void attn_kernel(
    const bf16* __restrict__ qb, const bf16* __restrict__ kb,
    const bf16* __restrict__ vtb, bf16* __restrict__ yws) {
  // steady-state layout: Ks [0,8192) | Vts [8192,18432) | Ps [18432,36864)
  // transient Qs [0,16384) overlays Ks + Vts rows 0..63 (dead after hoist);
  // Vts ones-rows live at [16384,18432) -> never clobbered by Qs.
  __shared__ __align__(16) uint8_t smem[36864];
  bf16* Ks  = (bf16*)smem;              // [64][64]   8192 B
  bf16* Vts = (bf16*)(smem + 8192);     // [80][64]  10240 B (rows 64..79 ones)
  bf16* Ps  = (bf16*)(smem + 18432);    // 2 bufs x 4 waves x 16 x PSTRIDE
  bf16* Qs  = (bf16*)smem;              // transient [2][64][64] 16384 B

  const int tid = threadIdx.x, lane = tid & 63, wid = tid >> 6;
  const int quad = lane >> 4, l15 = lane & 15;
  const int bh = blockIdx.x, b = bh >> 4, h = bh & 15;
  const int p = blockIdx.y;
  const int qts[2] = {31 - p, p};  // descending activity; 31-p >= 16 > p
  const float NEG_INF = -__builtin_inff();
  const float SCL = 0.125f * 1.44269504088896340736f;  // 1/sqrt(64) * log2(e)
  const float M0 = 20.0f;

  // stage 2 Q tiles [64][64] each, granule-swizzled: 1024 granules / 256 thr
#pragma unroll
  for (int j = 0; j < 4; j++) {
    const int g = j * 256 + tid;
    const int t = g >> 9, s = g & 511;
    const int row = s >> 3, gg = (s & 7) ^ (row & 7);
    gload_lds16(qb + ((long)(b * 2048 + qts[t] * 64 + row)) * 1024 + h * 64 + gg * 8,
                Qs + t * 4096 + s * 8);
  }
  {  // ones rows of Vts (outside Qs overlay, never overwritten by staging)
    union { ushort4 u4; bf16 h[4]; } one;
    one.h[0] = one.h[1] = one.h[2] = one.h[3] = (bf16)1.0f;
    *(ushort4*)(Vts + 64 * 64 + tid * 4) = one.u4;
  }
  __syncthreads();

  // hoist loop-invariant Q fragments (2 tiles x 2 k-chunks)
  bf16x8 qf[2][2];
  {
    const int row = wid * 16 + l15;
#pragma unroll
    for (int t = 0; t < 2; t++)
#pragma unroll
      for (int ks = 0; ks < 2; ks++)
        qf[t][ks] = *(const bf16x8*)(Qs + t * 4096 + row * 64 +
                                     (((ks * 4 + quad) ^ (row & 7)) * 8));
  }
  __syncthreads();  // all waves done reading Qs before K/V staging overwrites

  const bf16* kbase = kb + ((long)bh) * (2048L * 64);
  const bf16* vbase = vtb + ((long)bh) * (64L * 2048);
  floatx4 o[2][5] = {};
  bf16* pw0 = Ps + wid * (16 * PSTRIDE);
  bf16* pw1 = pw0 + 4 * 16 * PSTRIDE;

  const int ktmax = qts[0];
  for (int kt = 0; kt <= ktmax; kt++) {
    const int k0 = kt * 64;
    const int nact = 1 + (kt <= qts[1]);
    {
      int s = tid;
      int row = s >> 3, gg = (s & 7) ^ (row & 7);
      gload_lds16(kbase + (long)(k0 + row) * 64 + gg * 8, Ks + s * 8);
      gload_lds16(vbase + (long)row * 2048 + k0 + gg * 8, Vts + s * 8);
      s = tid + 256; row = s >> 3; gg = (s & 7) ^ (row & 7);
      gload_lds16(kbase + (long)(k0 + row) * 64 + gg * 8, Ks + s * 8);
      gload_lds16(vbase + (long)row * 2048 + k0 + gg * 8, Vts + s * 8);
    }
    __syncthreads();

    // ---- S = Q K^T for active tiles, one pass over shared K fragments ----
    floatx4 S[2][4] = {};
    __builtin_amdgcn_s_setprio(1);
#pragma unroll
    for (int ni = 0; ni < 4; ni++) {
      const int row = ni * 16 + l15;
#pragma unroll
      for (int ks = 0; ks < 2; ks++) {
        bf16x8 kf = *(const bf16x8*)(Ks + row * 64 + (((ks * 4 + quad) ^ (row & 7)) * 8));
        S[0][ni] = MFMA16(qf[0][ks], kf, S[0][ni]);
        if (nact > 1) S[1][ni] = MFMA16(qf[1][ks], kf, S[1][ni]);
      }
    }
    __builtin_amdgcn_s_setprio(0);

    // ---- softmax -> P buffers -> PV ----
    {
      const bool d0 = (kt == qts[0]), d1 = (kt == qts[1]);
#pragma unroll
      for (int ni = 0; ni < 4; ni++)
#pragma unroll
        for (int r = 0; r < 4; r++) {
          float v0 = S[0][ni][r] * SCL - M0;
          if (d0 && (ni * 16 + l15 > wid * 16 + quad * 4 + r)) v0 = NEG_INF;
          pw0[(quad * 4 + r) * PSTRIDE + ni * 16 + l15] = (bf16)EXP2F(v0);
        }
      if (nact > 1) {
#pragma unroll
        for (int ni = 0; ni < 4; ni++)
#pragma unroll
          for (int r = 0; r < 4; r++) {
            float v1 = S[1][ni][r] * SCL - M0;
            if (d1 && (ni * 16 + l15 > wid * 16 + quad * 4 + r)) v1 = NEG_INF;
            pw1[(quad * 4 + r) * PSTRIDE + ni * 16 + l15] = (bf16)EXP2F(v1);
          }
      }
      asm volatile("s_waitcnt lgkmcnt(0)" ::: "memory");
      bf16x8 pf0[2], pf1[2];
#pragma unroll
      for (int ks = 0; ks < 2; ks++)
        pf0[ks] = *(const bf16x8*)(pw0 + l15 * PSTRIDE + ks * 32 + quad * 8);
      if (nact > 1) {
#pragma unroll
        for (int ks = 0; ks < 2; ks++)
          pf1[ks] = *(const bf16x8*)(pw1 + l15 * PSTRIDE + ks * 32 + quad * 8);
      }
      __builtin_amdgcn_s_setprio(1);
#pragma unroll
      for (int ni = 0; ni < 5; ni++) {
        const int vrow = ni * 16 + l15;
#pragma unroll
        for (int ks = 0; ks < 2; ks++) {
          bf16x8 vf = *(const bf16x8*)(Vts + vrow * 64 + (((ks * 4 + quad) ^ (vrow & 7)) * 8));
          o[0][ni] = MFMA16(pf0[ks], vf, o[0][ni]);
          if (nact > 1) o[1][ni] = MFMA16(pf1[ks], vf, o[1][ni]);
        }
      }
      __builtin_amdgcn_s_setprio(0);
    }
    __syncthreads();
  }

  // ---- epilogue: 2 tiles; l = o[t][4] ----
#pragma unroll
  for (int t = 0; t < 2; t++) {
    const int q0 = qts[t] * 64;
    float inv[4];
#pragma unroll
    for (int r = 0; r < 4; r++) inv[r] = 1.0f / o[t][4][r];
    const long ybase = ((long)(b * 2048 + q0 + wid * 16 + quad * 4)) * 1024 + h * 64;
#pragma unroll
    for (int ni = 0; ni < 4; ni++)
#pragma unroll
      for (int r = 0; r < 4; r++)
        yws[ybase + (long)r * 1024 + ni * 16 + l15] = (bf16)(o[t][ni][r] * inv[r]);
  }
}

// ---------------------------------------------------------------------------
// Output projection: [8192,1024] x [1024,1024]^T -> y fp32; same pipelined
// BK=64 dbuf structure, hardened barriers, XCD-chunked swizzle.
// ---------------------------------------------------------------------------
__global__ __launch_bounds__(256, 2) void gemm_proj(
    const bf16* __restrict__ A, const bf16* __restrict__ Bw,
    const float* __restrict__ bp, float* __restrict__ y) {
  __shared__ __align__(16) bf16 As[2][128 * 64];
  __shared__ __align__(16) bf16 Bs[2][128 * 64];
  const int tid = threadIdx.x;
  const int lane = tid & 63, wid = tid >> 6;
  const int quad = lane >> 4, l15 = lane & 15;
  const int wm = wid >> 1, wn = wid & 1;

  // bijective XCD swizzle: grid (8,64) -> 512 blocks, 64/XCD
  const int lin = blockIdx.y * 8 + blockIdx.x;
  const int xcd = lin & 7, j = lin >> 3;      // j in [0,64)
  const int bx = j >> 3;                      // [0,8) n-tile
  const int by = (xcd << 3) | (j & 7);        // [0,64) m-tile
  const long m0 = (long)by * 128;
  const long n0 = (long)bx * 128;

  const int gg = (tid & 7) ^ ((tid >> 3) & 7);
  const bf16* aSrc = A + (m0 + (tid >> 3)) * 1024 + gg * 8;
  const bf16* bSrc = Bw + (n0 + (tid >> 3)) * 1024 + gg * 8;

#define PROJ_STAGE(buf, k0)                                                 \
  {                                                                         \
    _Pragma("unroll")                                                       \
    for (int jj = 0; jj < 4; jj++) {                                        \
      gload_lds16(aSrc + (k0) + jj * (32 * 1024), &As[buf][(tid + jj * 256) * 8]); \
      gload_lds16(bSrc + (k0) + jj * (32 * 1024), &Bs[buf][(tid + jj * 256) * 8]); \
    }                                                                       \
  }

  floatx4 acc[4][4] = {};

  PROJ_STAGE(0, 0);
  for (int kt = 0; kt < 16; kt++) {
    const int cur = kt & 1;
    if (kt < 15) {
      PROJ_STAGE(cur ^ 1, (kt + 1) * 64);
      BAR_VM(8);
    } else {
      BAR_VM(0);
    }
    const bf16* Ac = &As[cur][0];
    const bf16* Bc = &Bs[cur][0];
    __builtin_amdgcn_s_setprio(1);
#pragma unroll
    for (int ks = 0; ks < 2; ks++) {
      bf16x8 af[4], bfr[4];
#pragma unroll
      for (int mi = 0; mi < 4; mi++) {
        int row = wm * 64 + mi * 16 + l15;
        af[mi] = *(const bf16x8*)(Ac + row * 64 + (((ks * 4 + quad) ^ (row & 7)) * 8));
      }
#pragma unroll
      for (int ni = 0; ni < 4; ni++) {
        int row = wn * 64 + ni * 16 + l15;
        bfr[ni] = *(const bf16x8*)(Bc + row * 64 + (((ks * 4 + quad) ^ (row & 7)) * 8));
      }
#pragma unroll
      for (int mi = 0; mi < 4; mi++)
#pragma unroll
        for (int ni = 0; ni < 4; ni++)
          acc[mi][ni] = MFMA16(af[mi], bfr[ni], acc[mi][ni]);
    }
    __builtin_amdgcn_s_setprio(0);
    BAR_LGKM0();
  }
#undef PROJ_STAGE

#pragma unroll
  for (int ni = 0; ni < 4; ni++) {
    const long n = n0 + wn * 64 + ni * 16 + l15;
    const float bias = bp[n];
#pragma unroll
    for (int mi = 0; mi < 4; mi++) {
      const long mb = m0 + wm * 64 + mi * 16 + quad * 4;
      floatx4 a = acc[mi][ni];
#pragma unroll
      for (int r = 0; r < 4; r++) y[(mb + r) * 1024 + n] = a[r] + bias;
    }
  }
}

// ---------------------------------------------------------------------------
extern "C" void kernel_launch(void* const* d_in, const int* in_sizes, int n_in,
                              void* d_out, int out_size, void* d_ws, size_t ws_size,
                              hipStream_t stream) {
  const float* x  = (const float*)d_in[0];
  const float* Wq = (const float*)d_in[1];
  const float* bq = (const float*)d_in[2];
  const float* Wk = (const float*)d_in[3];
  const float* bk = (const float*)d_in[4];
  const float* Wv = (const float*)d_in[5];
  const float* bv = (const float*)d_in[6];
  const float* Wp = (const float*)d_in[7];
  const float* bp = (const float*)d_in[8];

  float* y  = (float*)d_out;                 // [B,T,C] = 8388608
  float* pk = y + 8388608;                   // present[0] = k [B,H,T,D]
  float* pv = pk + 8388608;                  // present[1] = v [B,H,T,D]

  uint8_t* ws = (uint8_t*)d_ws;
  bf16* xb    = (bf16*)(ws);                    // 16 MB  [8192,1024]
  bf16* wqkvb = (bf16*)(ws + (16L << 20));      //  6 MB  [3072,1024]
  bf16* wpb   = (bf16*)(ws + (22L << 20));      //  2 MB  [1024,1024]
  bf16* qb    = (bf16*)(ws + (24L << 20));      // 16 MB  [B,T,C]
  bf16* kbf   = (bf16*)(ws + (40L << 20));      // 16 MB  [B,H,T,D]
  bf16* vtb   = (bf16*)(ws + (56L << 20));      // 16 MB  [B,H,D,T]
  bf16* yws   = (bf16*)(ws + (72L << 20));      // 16 MB  [B,T,C]

  convert_kernel<<<12288, 256, 0, stream>>>(x, Wq, Wk, Wv, Wp, xb, wqkvb, wpb);
  gemm_qkv<<<dim3(24, 64), 256, 0, stream>>>(xb, wqkvb, bq, bk, bv, qb, kbf, pk, pv, vtb);
  attn_kernel<<<dim3(64, 16), 256, 0, stream>>>(qb, kbf, vtb, yws);
  gemm_proj<<<dim3(8, 64), 256, 0, stream>>>(yws, wpb, bp, y);
}